// Round 7
// baseline (853.479 us; speedup 1.0000x reference)
//
#include <hip/hip_runtime.h>
#include <math.h>

// StyleGAN2 StyledConvUp, B=16, Cin=Cout=512, 32x32 -> 64x64. fp32 I/O.
// Round 11: round-10 GEMM structure (tap-folded K, XOR-swizzled LDS, T14
// issue-early/write-late) with three safe changes:
//  1) launch_bounds(256,3): 3 blocks/CU (144KB LDS) for cross-block overlap
//  2) batch-PAIR N tiling: N=2178 -> 9x256 tiles (5.8% pad vs 17.5%), one
//     pair per XCD (S2 ws 2.36MB, L2-resident); g=1 fallback for nb==1
//  3) I row stride 1096 -> 1152 (2304B = 18 cache lines, line-aligned rows;
//     round-10 WRITE amplification suspect) + k_blur float4 out-phase.

typedef __attribute__((ext_vector_type(8))) __bf16 bf16x8;
typedef __attribute__((ext_vector_type(4))) float f32x4;

#define WSCALE 0.014731391274719739f      /* 1/sqrt(512*9) */
#define SSCALE 0.044194173824159216f      /* 1/sqrt(512)   */
#define ISTRIDE 1152

__device__ __forceinline__ unsigned short f2bf(float f) {
  unsigned u = __builtin_bit_cast(unsigned, f);
  u += 0x7fff + ((u >> 16) & 1);             // RTNE, finite inputs
  return (unsigned short)(u >> 16);
}
__device__ __forceinline__ float bf2f(unsigned short h) {
  unsigned u = ((unsigned)h) << 16;
  return __builtin_bit_cast(float, u);
}

// ---- s[b,ic] ----
__global__ __launch_bounds__(256) void k_style(
    const float* __restrict__ style, const float* __restrict__ mod_w,
    const float* __restrict__ mod_b, float* __restrict__ s_out) {
  int wid  = (blockIdx.x * 256 + threadIdx.x) >> 6;
  int lane = threadIdx.x & 63;
  int b = wid >> 9, ic = wid & 511;
  float acc = 0.f;
  for (int j = lane; j < 512; j += 64)
    acc += style[b * 512 + j] * mod_w[ic * 512 + j];
  for (int off = 32; off > 0; off >>= 1) acc += __shfl_down(acc, off);
  if (lane == 0) s_out[b * 512 + ic] = acc * SSCALE + mod_b[ic];
}

// slab order groups taps by parity: p0:{0,2,6,8} p1:{1,7} p2:{3,5} p3:{4}
__device__ const int SLABTAP[9] = {0, 2, 6, 8, 1, 7, 3, 5, 4};
__device__ const int SLABOFF[4] = {0, 4, 6, 8};
__device__ const int TAPN[4]    = {4, 2, 2, 1};
__device__ const int TOFFp[4][4] = {{0,-1,-34,-35},{0,-34,0,0},{0,-1,0,0},{0,0,0,0}};

// ---- W2[(slab*512+oc)][ic] bf16 (parity-ordered tap slabs) + w2s = sum_t w^2 ----
__global__ __launch_bounds__(256) void k_w2(
    const float* __restrict__ conv_w, unsigned short* __restrict__ W2,
    float* __restrict__ w2s) {
  __shared__ float t[4608];
  const int oc = blockIdx.x;
  for (int i = threadIdx.x; i < 4608; i += 256) t[i] = conv_w[oc * 4608 + i];
  __syncthreads();
  for (int i = threadIdx.x; i < 4608; i += 256) {
    int tg = i >> 9, ic = i & 511;
    W2[((size_t)(tg * 512 + oc)) * 512 + ic] = f2bf(t[ic * 9 + SLABTAP[tg]]);
  }
  for (int i = threadIdx.x; i < 512; i += 256) {
    float a = 0.f;
    #pragma unroll
    for (int tg = 0; tg < 9; tg++) { float w = t[i * 9 + tg]; a += w * w; }
    w2s[oc * 512 + i] = a;
  }
}

// ---- dscale[b,oc] ----
__global__ __launch_bounds__(256) void k_demod(
    const float* __restrict__ w2s, const float* __restrict__ s,
    float* __restrict__ dscale) {
  int wid  = (blockIdx.x * 256 + threadIdx.x) >> 6;
  int lane = threadIdx.x & 63;
  int b = wid >> 9, oc = wid & 511;
  float acc = 0.f;
  for (int ic = lane; ic < 512; ic += 64) {
    float sv = s[b * 512 + ic];
    acc += sv * sv * w2s[oc * 512 + ic];
  }
  for (int off = 32; off > 0; off >>= 1) acc += __shfl_down(acc, off);
  if (lane == 0)
    dscale[b * 512 + oc] = WSCALE * rsqrtf(WSCALE * WSCALE * acc + 1e-8f);
}

// ---- S2[b][R=ry*34+rx][ic] = x*s pixel-major bf16; interior ry,rx in 1..32
//      maps to x row ry-1, col rx-1; border rows zeroed by k_zero. ----
__global__ __launch_bounds__(256) void k_xs2(
    const float* __restrict__ x, const float* __restrict__ s,
    unsigned short* __restrict__ S2) {
  __shared__ float xt[64][65];
  const int b = blockIdx.z, ic0 = blockIdx.y * 64, r0 = blockIdx.x * 2;
  for (int i = threadIdx.x; i < 4096; i += 256) {
    int icL = i >> 6, pxL = i & 63;
    int gr = r0 + (pxL >> 5), gc = pxL & 31;
    xt[icL][pxL] = x[((b * 512 + ic0 + icL) * 32 + gr) * 32 + gc] * s[b * 512 + ic0 + icL];
  }
  __syncthreads();
  for (int i = threadIdx.x; i < 512; i += 256) {
    int pxL = i >> 3, icO = i & 7;
    unsigned short tmp[8];
    #pragma unroll
    for (int k = 0; k < 8; k++) tmp[k] = f2bf(xt[icO * 8 + k][pxL]);
    int gr = r0 + (pxL >> 5), gc = pxL & 31;
    int R = (gr + 1) * 34 + (gc + 1);
    *(uint4*)(&S2[((size_t)b * 1156 + R) * 512 + ic0 + icO * 8]) = *(const uint4*)tmp;
  }
}

// ---- zero the 132 border rows of each S2[b] plane ----
__global__ void k_zero(unsigned short* __restrict__ S2) {
  int b = blockIdx.y, id = blockIdx.x;
  int ry, rx;
  if (id < 34)       { ry = 0;        rx = id; }
  else if (id < 68)  { ry = 33;       rx = id - 34; }
  else if (id < 100) { ry = id - 67;  rx = 0; }
  else               { ry = id - 99;  rx = 33; }
  ((unsigned*)(S2 + ((size_t)b * 1156 + ry * 34 + rx) * 512))[threadIdx.x] = 0;
}

// ---- GEMM-P: per (batch-group, parity): I_p[oc][n], n flat over g batches
//      (g*1089 px). 128x256 block, BK=64, XOR-swizzled LDS, T14 pipeline. ----
__global__ __launch_bounds__(256, 3) void k_gemm(
    const unsigned short* __restrict__ S2, const unsigned short* __restrict__ W2,
    const float* __restrict__ dscale, unsigned short* __restrict__ I,
    int b_base, int g, int ntiles, int run) {
  __shared__ __align__(16) unsigned short As[128][64];   // 16 KB
  __shared__ __align__(16) unsigned short Bs[256][64];   // 32 KB

  // bijective XCD swizzle on the 1-D grid (nblk % 8 == 0 by construction).
  const int nblk = gridDim.x, qq = nblk >> 3, lid = blockIdx.x;
  const int swz = (lid & 7) * qq + (lid >> 3);
  const int grp = swz / run;  int rr = swz - grp * run;
  const int p  = rr / (ntiles << 2);  rr -= p * (ntiles << 2);
  const int nt = rr >> 2, mt = rr & 3;
  const int m0 = mt * 128, n0 = nt * 256;
  const int Ngrp = g * 1089;

  const int tid = threadIdx.x, lane = tid & 63;
  const int wv = tid >> 6, wm = wv >> 1, wn = wv & 1;
  const int l15 = lane & 15, quad = lane >> 4;
  const int ntap = TAPN[p], soff = SLABOFF[p];
  const int kq = tid & 7, rw = tid >> 3;

  // hoist B-row decode (step-invariant): flat n -> padded S2 row base
  int gRow[8];
  #pragma unroll
  for (int it = 0; it < 8; it++) {
    int n = n0 + it * 32 + rw;
    if (n < Ngrp) {
      int bl2 = n / 1089;
      int u = n - bl2 * 1089;
      int uy = u / 33, ux = u - uy * 33;
      gRow[it] = (b_base + grp * g + bl2) * 1156 + (uy + 1) * 34 + (ux + 1);
    } else gRow[it] = -1;
  }

  f32x4 acc[4][8];
  #pragma unroll
  for (int m = 0; m < 4; m++)
    #pragma unroll
    for (int n = 0; n < 8; n++) acc[m][n] = (f32x4)0.f;

  const int kend = ntap * 512;

  // prologue: stage tile 0 into registers
  uint4 ra[4], rb[8];
  {
    const int off0 = TOFFp[p][0];
    #pragma unroll
    for (int it = 0; it < 4; it++)
      ra[it] = *(const uint4*)(W2 + ((size_t)(soff * 512 + m0 + it * 32 + rw)) * 512 + kq * 8);
    #pragma unroll
    for (int it = 0; it < 8; it++) {
      uint4 v = make_uint4(0u, 0u, 0u, 0u);
      if (gRow[it] >= 0)
        v = *(const uint4*)(S2 + (size_t)(gRow[it] + off0) * 512 + kq * 8);
      rb[it] = v;
    }
  }

  #pragma unroll 1
  for (int k0 = 0; k0 < kend; k0 += 64) {
    __syncthreads();                      // waves done reading LDS (prev iter)
    // commit staged tile t to LDS
    #pragma unroll
    for (int it = 0; it < 4; it++) {
      int r = it * 32 + rw;
      *(uint4*)(&As[r][(kq ^ (r & 7)) * 8]) = ra[it];
    }
    #pragma unroll
    for (int it = 0; it < 8; it++) {
      int r = it * 32 + rw;
      *(uint4*)(&Bs[r][(kq ^ (r & 7)) * 8]) = rb[it];
    }
    // issue tile t+1 global loads now; they land under tile t's MFMA
    const int k1 = k0 + 64;
    if (k1 < kend) {
      const int tj1   = k1 >> 9;
      const int icw1  = k1 & 511;
      const int off1  = TOFFp[p][tj1];
      const int slab1 = soff + tj1;
      #pragma unroll
      for (int it = 0; it < 4; it++)
        ra[it] = *(const uint4*)(W2 + ((size_t)(slab1 * 512 + m0 + it * 32 + rw)) * 512 + icw1 + kq * 8);
      #pragma unroll
      for (int it = 0; it < 8; it++) {
        uint4 v = make_uint4(0u, 0u, 0u, 0u);
        if (gRow[it] >= 0)
          v = *(const uint4*)(S2 + (size_t)(gRow[it] + off1) * 512 + icw1 + kq * 8);
        rb[it] = v;
      }
    }
    __syncthreads();                      // tile t visible in LDS
    #pragma unroll
    for (int kk = 0; kk < 2; kk++) {
      bf16x8 af[4], bfr[8];
      #pragma unroll
      for (int m = 0; m < 4; m++) {
        int r = wm * 64 + m * 16 + l15;
        af[m] = *(const bf16x8*)(&As[r][((kk * 4 + quad) ^ (r & 7)) * 8]);
      }
      #pragma unroll
      for (int n = 0; n < 8; n++) {
        int r = wn * 128 + n * 16 + l15;
        bfr[n] = *(const bf16x8*)(&Bs[r][((kk * 4 + quad) ^ (r & 7)) * 8]);
      }
      #pragma unroll
      for (int m = 0; m < 4; m++)
        #pragma unroll
        for (int n = 0; n < 8; n++)
          acc[m][n] = __builtin_amdgcn_mfma_f32_16x16x32_bf16(af[m], bfr[n], acc[m][n], 0, 0, 0);
    }
  }

  // epilogue: demod scale -> bf16 into I[blA][p][oc][ul] (stride ISTRIDE)
  #pragma unroll
  for (int n = 0; n < 8; n++) {
    int nf = n0 + wn * 128 + n * 16 + l15;
    if (nf < Ngrp) {
      int bl2 = nf / 1089;
      int ul  = nf - bl2 * 1089;
      int blA = grp * g + bl2;
      int bgl = b_base + blA;
      const size_t Ibase = ((size_t)(blA * 4 + p) * 512) * ISTRIDE;
      #pragma unroll
      for (int m = 0; m < 4; m++) {
        int oc = m0 + wm * 64 + m * 16 + quad * 4;
        #pragma unroll
        for (int r = 0; r < 4; r++) {
          float ds = dscale[bgl * 512 + oc + r];
          I[Ibase + (size_t)(oc + r) * ISTRIDE + ul] = f2bf(acc[m][n][r] * ds);
        }
      }
    }
  }
}

// ---- blur + noise + bias + lrelu: one block per (oc, bl); 2-phase ----
__global__ __launch_bounds__(256) void k_blur(
    const unsigned short* __restrict__ I, const float* __restrict__ noise,
    const float* __restrict__ noise_w, const float* __restrict__ act_b,
    float* __restrict__ out, int b_base) {
  __shared__ __align__(16) unsigned short Ism[4][1096];
  __shared__ float V[64][67];
  const int oc = blockIdx.x, bl = blockIdx.y, b = b_base + bl;
  for (int i = threadIdx.x; i < 548; i += 256) {
    int p = i / 137, w = i - p * 137;
    *(uint4*)(&Ism[p][w * 8]) =
        *(const uint4*)(I + ((size_t)(bl * 4 + p) * 512 + oc) * ISTRIDE + w * 8);
  }
  __syncthreads();
  // vertical: V[qy][px*33+ux], planes p = py*2+px
  for (int i = threadIdx.x; i < 2112; i += 256) {
    int r = i / 66, col = i - r * 66;
    int px_ = (col >= 33), ux = col - 33 * px_;
    float v0 = (r >= 1) ? bf2f(Ism[2 + px_][(r - 1) * 33 + ux]) : 0.f;
    float a_ = bf2f(Ism[px_][r * 33 + ux]);
    float b_ = bf2f(Ism[2 + px_][r * 33 + ux]);
    float c_ = bf2f(Ism[px_][(r + 1) * 33 + ux]);
    float d_ = bf2f(Ism[2 + px_][(r + 1) * 33 + ux]);
    V[2 * r][col]     = 0.25f * v0 + 0.75f * a_ + 0.75f * b_ + 0.25f * c_;
    V[2 * r + 1][col] = 0.25f * a_ + 0.75f * b_ + 0.75f * c_ + 0.25f * d_;
  }
  __syncthreads();
  const float nw = noise_w[0], ab = act_b[oc];
  // horizontal: 4 output px per thread, float4 stores
  for (int i = threadIdx.x; i < 1024; i += 256) {
    int qy = i >> 4, r4 = i & 15;
    int rx = r4 * 2;
    float vA0 = V[qy][rx],     vB0 = V[qy][33 + rx];
    float vA1 = V[qy][rx + 1], vB1 = V[qy][33 + rx + 1];
    float vA2 = V[qy][rx + 2], vB2 = V[qy][33 + rx + 2];
    float w0 = (rx >= 1) ? V[qy][33 + rx - 1] : 0.f;
    float o0 = 0.25f * w0  + 0.75f * vA0 + 0.75f * vB0 + 0.25f * vA1;
    float o1 = 0.25f * vA0 + 0.75f * vB0 + 0.75f * vA1 + 0.25f * vB1;
    float o2 = 0.25f * vB0 + 0.75f * vA1 + 0.75f * vB1 + 0.25f * vA2;
    float o3 = 0.25f * vA1 + 0.75f * vB1 + 0.75f * vA2 + 0.25f * vB2;
    const float4 nv = *(const float4*)(noise + b * 4096 + qy * 64 + r4 * 4);
    o0 += nw * nv.x + ab;  o1 += nw * nv.y + ab;
    o2 += nw * nv.z + ab;  o3 += nw * nv.w + ab;
    o0 = (o0 > 0.f ? o0 : 0.2f * o0) * 1.4142135623730951f;
    o1 = (o1 > 0.f ? o1 : 0.2f * o1) * 1.4142135623730951f;
    o2 = (o2 > 0.f ? o2 : 0.2f * o2) * 1.4142135623730951f;
    o3 = (o3 > 0.f ? o3 : 0.2f * o3) * 1.4142135623730951f;
    float4 ov = make_float4(o0, o1, o2, o3);
    *(float4*)(out + (((size_t)b * 512 + oc) * 64 + qy) * 64 + r4 * 4) = ov;
  }
}

extern "C" void kernel_launch(void* const* d_in, const int* in_sizes, int n_in,
                              void* d_out, int out_size, void* d_ws, size_t ws_size,
                              hipStream_t stream) {
  const float* x       = (const float*)d_in[0];
  const float* style   = (const float*)d_in[1];
  const float* noise   = (const float*)d_in[2];
  const float* conv_w  = (const float*)d_in[3];
  const float* mod_w   = (const float*)d_in[4];
  const float* mod_b   = (const float*)d_in[5];
  const float* noise_w = (const float*)d_in[6];
  const float* act_b   = (const float*)d_in[7];
  float* out = (float*)d_out;

  char* ws = (char*)d_ws;
  float*          s_ws = (float*)ws;                                  // 32 KB
  float*          d_sc = (float*)(ws + 32768);                        // 32 KB
  float*          w2s  = (float*)(ws + 65536);                        // 1 MB
  unsigned short* S2   = (unsigned short*)(ws + 65536 + 1048576);               // 18.94 MB
  unsigned short* W2   = (unsigned short*)(ws + 65536 + 1048576 + 18939904);    // 4.72 MB
  unsigned short* I    = (unsigned short*)(ws + 65536 + 1048576 + 18939904 + 4718592);
  const size_t fixed = 65536ull + 1048576ull + 18939904ull + 4718592ull;  // 24.77 MB
  const size_t per_b = (size_t)4 * 512 * ISTRIDE * 2;                     // 4.72 MB/batch

  int nb = 16;                                  // batch chunk sized to ws budget
  if (ws_size < fixed + 16 * per_b) nb = 8;
  if (ws_size < fixed + 8 * per_b)  nb = 4;
  if (ws_size < fixed + 4 * per_b)  nb = 2;
  if (ws_size < fixed + 2 * per_b)  nb = 1;

  k_style<<<2048, 256, 0, stream>>>(style, mod_w, mod_b, s_ws);
  k_w2<<<512, 256, 0, stream>>>(conv_w, W2, w2s);
  k_demod<<<2048, 256, 0, stream>>>(w2s, s_ws, d_sc);
  k_xs2<<<dim3(16, 8, 16), 256, 0, stream>>>(x, s_ws, S2);
  k_zero<<<dim3(132, 16), 256, 0, stream>>>(S2);
  for (int b0 = 0; b0 < 16; b0 += nb) {
    int g      = (nb >= 2) ? 2 : 1;         // batches per N-group
    int ngrp   = nb / g;
    int ntiles = (g * 1089 + 255) / 256;    // 9 (g=2) or 5 (g=1)
    int run    = 4 * ntiles * 4;            // blocks per group (144 or 80)
    k_gemm<<<ngrp * run, 256, 0, stream>>>(S2, W2, d_sc, I, b0, g, ntiles, run);
    k_blur<<<dim3(512, nb), 256, 0, stream>>>(I, noise, noise_w, act_b, out, b0);
  }
}

// Round 9
// 401.687 us; speedup vs baseline: 2.1247x; 2.1247x over previous
//
#include <hip/hip_runtime.h>
#include <math.h>

// StyleGAN2 StyledConvUp, B=16, Cin=Cout=512, 32x32 -> 64x64. fp32 I/O.
// Round 13: resubmission of round 12 (container-level infra failure, no
// counter evidence of a kernel fault; round 11 passed with identical layout
// and the (256,2) bound is round-10-verified). Content:
//  - round-10 GEMM structure (tap-folded K, XOR-swizzled LDS, T14 pipeline)
//  - launch_bounds(256,2)  [(256,3) spilled: VGPR 116->84, 2.7GB scratch]
//  - batch-PAIR N tiling: N=2178 -> 9x256 tiles (5.8% pad vs 17.5%)
//  - I row stride 1152 (2304B, line-aligned) + k_blur float4 out-phase.

typedef __attribute__((ext_vector_type(8))) __bf16 bf16x8;
typedef __attribute__((ext_vector_type(4))) float f32x4;

#define WSCALE 0.014731391274719739f      /* 1/sqrt(512*9) */
#define SSCALE 0.044194173824159216f      /* 1/sqrt(512)   */
#define ISTRIDE 1152

__device__ __forceinline__ unsigned short f2bf(float f) {
  unsigned u = __builtin_bit_cast(unsigned, f);
  u += 0x7fff + ((u >> 16) & 1);             // RTNE, finite inputs
  return (unsigned short)(u >> 16);
}
__device__ __forceinline__ float bf2f(unsigned short h) {
  unsigned u = ((unsigned)h) << 16;
  return __builtin_bit_cast(float, u);
}

// ---- s[b,ic] ----
__global__ __launch_bounds__(256) void k_style(
    const float* __restrict__ style, const float* __restrict__ mod_w,
    const float* __restrict__ mod_b, float* __restrict__ s_out) {
  int wid  = (blockIdx.x * 256 + threadIdx.x) >> 6;
  int lane = threadIdx.x & 63;
  int b = wid >> 9, ic = wid & 511;
  float acc = 0.f;
  for (int j = lane; j < 512; j += 64)
    acc += style[b * 512 + j] * mod_w[ic * 512 + j];
  for (int off = 32; off > 0; off >>= 1) acc += __shfl_down(acc, off);
  if (lane == 0) s_out[b * 512 + ic] = acc * SSCALE + mod_b[ic];
}

// slab order groups taps by parity: p0:{0,2,6,8} p1:{1,7} p2:{3,5} p3:{4}
__device__ const int SLABTAP[9] = {0, 2, 6, 8, 1, 7, 3, 5, 4};
__device__ const int SLABOFF[4] = {0, 4, 6, 8};
__device__ const int TAPN[4]    = {4, 2, 2, 1};
__device__ const int TOFFp[4][4] = {{0,-1,-34,-35},{0,-34,0,0},{0,-1,0,0},{0,0,0,0}};

// ---- W2[(slab*512+oc)][ic] bf16 (parity-ordered tap slabs) + w2s = sum_t w^2 ----
__global__ __launch_bounds__(256) void k_w2(
    const float* __restrict__ conv_w, unsigned short* __restrict__ W2,
    float* __restrict__ w2s) {
  __shared__ float t[4608];
  const int oc = blockIdx.x;
  for (int i = threadIdx.x; i < 4608; i += 256) t[i] = conv_w[oc * 4608 + i];
  __syncthreads();
  for (int i = threadIdx.x; i < 4608; i += 256) {
    int tg = i >> 9, ic = i & 511;
    W2[((size_t)(tg * 512 + oc)) * 512 + ic] = f2bf(t[ic * 9 + SLABTAP[tg]]);
  }
  for (int i = threadIdx.x; i < 512; i += 256) {
    float a = 0.f;
    #pragma unroll
    for (int tg = 0; tg < 9; tg++) { float w = t[i * 9 + tg]; a += w * w; }
    w2s[oc * 512 + i] = a;
  }
}

// ---- dscale[b,oc] ----
__global__ __launch_bounds__(256) void k_demod(
    const float* __restrict__ w2s, const float* __restrict__ s,
    float* __restrict__ dscale) {
  int wid  = (blockIdx.x * 256 + threadIdx.x) >> 6;
  int lane = threadIdx.x & 63;
  int b = wid >> 9, oc = wid & 511;
  float acc = 0.f;
  for (int ic = lane; ic < 512; ic += 64) {
    float sv = s[b * 512 + ic];
    acc += sv * sv * w2s[oc * 512 + ic];
  }
  for (int off = 32; off > 0; off >>= 1) acc += __shfl_down(acc, off);
  if (lane == 0)
    dscale[b * 512 + oc] = WSCALE * rsqrtf(WSCALE * WSCALE * acc + 1e-8f);
}

// ---- S2[b][R=ry*34+rx][ic] = x*s pixel-major bf16; interior ry,rx in 1..32
//      maps to x row ry-1, col rx-1; border rows zeroed by k_zero. ----
__global__ __launch_bounds__(256) void k_xs2(
    const float* __restrict__ x, const float* __restrict__ s,
    unsigned short* __restrict__ S2) {
  __shared__ float xt[64][65];
  const int b = blockIdx.z, ic0 = blockIdx.y * 64, r0 = blockIdx.x * 2;
  for (int i = threadIdx.x; i < 4096; i += 256) {
    int icL = i >> 6, pxL = i & 63;
    int gr = r0 + (pxL >> 5), gc = pxL & 31;
    xt[icL][pxL] = x[((b * 512 + ic0 + icL) * 32 + gr) * 32 + gc] * s[b * 512 + ic0 + icL];
  }
  __syncthreads();
  for (int i = threadIdx.x; i < 512; i += 256) {
    int pxL = i >> 3, icO = i & 7;
    unsigned short tmp[8];
    #pragma unroll
    for (int k = 0; k < 8; k++) tmp[k] = f2bf(xt[icO * 8 + k][pxL]);
    int gr = r0 + (pxL >> 5), gc = pxL & 31;
    int R = (gr + 1) * 34 + (gc + 1);
    *(uint4*)(&S2[((size_t)b * 1156 + R) * 512 + ic0 + icO * 8]) = *(const uint4*)tmp;
  }
}

// ---- zero the 132 border rows of each S2[b] plane ----
__global__ void k_zero(unsigned short* __restrict__ S2) {
  int b = blockIdx.y, id = blockIdx.x;
  int ry, rx;
  if (id < 34)       { ry = 0;        rx = id; }
  else if (id < 68)  { ry = 33;       rx = id - 34; }
  else if (id < 100) { ry = id - 67;  rx = 0; }
  else               { ry = id - 99;  rx = 33; }
  ((unsigned*)(S2 + ((size_t)b * 1156 + ry * 34 + rx) * 512))[threadIdx.x] = 0;
}

// ---- GEMM-P: per (batch-group, parity): I_p[oc][n], n flat over g batches
//      (g*1089 px). 128x256 block, BK=64, XOR-swizzled LDS, T14 pipeline. ----
__global__ __launch_bounds__(256, 2) void k_gemm(
    const unsigned short* __restrict__ S2, const unsigned short* __restrict__ W2,
    const float* __restrict__ dscale, unsigned short* __restrict__ I,
    int b_base, int g, int ntiles, int run) {
  __shared__ __align__(16) unsigned short As[128][64];   // 16 KB
  __shared__ __align__(16) unsigned short Bs[256][64];   // 32 KB

  // bijective XCD swizzle on the 1-D grid (nblk % 8 == 0 by construction).
  const int nblk = gridDim.x, qq = nblk >> 3, lid = blockIdx.x;
  const int swz = (lid & 7) * qq + (lid >> 3);
  const int grp = swz / run;  int rr = swz - grp * run;
  const int p  = rr / (ntiles << 2);  rr -= p * (ntiles << 2);
  const int nt = rr >> 2, mt = rr & 3;
  const int m0 = mt * 128, n0 = nt * 256;
  const int Ngrp = g * 1089;

  const int tid = threadIdx.x, lane = tid & 63;
  const int wv = tid >> 6, wm = wv >> 1, wn = wv & 1;
  const int l15 = lane & 15, quad = lane >> 4;
  const int ntap = TAPN[p], soff = SLABOFF[p];
  const int kq = tid & 7, rw = tid >> 3;

  // hoist B-row decode (step-invariant): flat n -> padded S2 row base
  int gRow[8];
  #pragma unroll
  for (int it = 0; it < 8; it++) {
    int n = n0 + it * 32 + rw;
    if (n < Ngrp) {
      int bl2 = n / 1089;
      int u = n - bl2 * 1089;
      int uy = u / 33, ux = u - uy * 33;
      gRow[it] = (b_base + grp * g + bl2) * 1156 + (uy + 1) * 34 + (ux + 1);
    } else gRow[it] = -1;
  }

  f32x4 acc[4][8];
  #pragma unroll
  for (int m = 0; m < 4; m++)
    #pragma unroll
    for (int n = 0; n < 8; n++) acc[m][n] = (f32x4)0.f;

  const int kend = ntap * 512;

  // prologue: stage tile 0 into registers
  uint4 ra[4], rb[8];
  {
    const int off0 = TOFFp[p][0];
    #pragma unroll
    for (int it = 0; it < 4; it++)
      ra[it] = *(const uint4*)(W2 + ((size_t)(soff * 512 + m0 + it * 32 + rw)) * 512 + kq * 8);
    #pragma unroll
    for (int it = 0; it < 8; it++) {
      uint4 v = make_uint4(0u, 0u, 0u, 0u);
      if (gRow[it] >= 0)
        v = *(const uint4*)(S2 + (size_t)(gRow[it] + off0) * 512 + kq * 8);
      rb[it] = v;
    }
  }

  #pragma unroll 1
  for (int k0 = 0; k0 < kend; k0 += 64) {
    __syncthreads();                      // waves done reading LDS (prev iter)
    // commit staged tile t to LDS
    #pragma unroll
    for (int it = 0; it < 4; it++) {
      int r = it * 32 + rw;
      *(uint4*)(&As[r][(kq ^ (r & 7)) * 8]) = ra[it];
    }
    #pragma unroll
    for (int it = 0; it < 8; it++) {
      int r = it * 32 + rw;
      *(uint4*)(&Bs[r][(kq ^ (r & 7)) * 8]) = rb[it];
    }
    // issue tile t+1 global loads now; they land under tile t's MFMA
    const int k1 = k0 + 64;
    if (k1 < kend) {
      const int tj1   = k1 >> 9;
      const int icw1  = k1 & 511;
      const int off1  = TOFFp[p][tj1];
      const int slab1 = soff + tj1;
      #pragma unroll
      for (int it = 0; it < 4; it++)
        ra[it] = *(const uint4*)(W2 + ((size_t)(slab1 * 512 + m0 + it * 32 + rw)) * 512 + icw1 + kq * 8);
      #pragma unroll
      for (int it = 0; it < 8; it++) {
        uint4 v = make_uint4(0u, 0u, 0u, 0u);
        if (gRow[it] >= 0)
          v = *(const uint4*)(S2 + (size_t)(gRow[it] + off1) * 512 + icw1 + kq * 8);
        rb[it] = v;
      }
    }
    __syncthreads();                      // tile t visible in LDS
    #pragma unroll
    for (int kk = 0; kk < 2; kk++) {
      bf16x8 af[4], bfr[8];
      #pragma unroll
      for (int m = 0; m < 4; m++) {
        int r = wm * 64 + m * 16 + l15;
        af[m] = *(const bf16x8*)(&As[r][((kk * 4 + quad) ^ (r & 7)) * 8]);
      }
      #pragma unroll
      for (int n = 0; n < 8; n++) {
        int r = wn * 128 + n * 16 + l15;
        bfr[n] = *(const bf16x8*)(&Bs[r][((kk * 4 + quad) ^ (r & 7)) * 8]);
      }
      #pragma unroll
      for (int m = 0; m < 4; m++)
        #pragma unroll
        for (int n = 0; n < 8; n++)
          acc[m][n] = __builtin_amdgcn_mfma_f32_16x16x32_bf16(af[m], bfr[n], acc[m][n], 0, 0, 0);
    }
  }

  // epilogue: demod scale -> bf16 into I[blA][p][oc][ul] (stride ISTRIDE)
  #pragma unroll
  for (int n = 0; n < 8; n++) {
    int nf = n0 + wn * 128 + n * 16 + l15;
    if (nf < Ngrp) {
      int bl2 = nf / 1089;
      int ul  = nf - bl2 * 1089;
      int blA = grp * g + bl2;
      int bgl = b_base + blA;
      const size_t Ibase = ((size_t)(blA * 4 + p) * 512) * ISTRIDE;
      #pragma unroll
      for (int m = 0; m < 4; m++) {
        int oc = m0 + wm * 64 + m * 16 + quad * 4;
        #pragma unroll
        for (int r = 0; r < 4; r++) {
          float ds = dscale[bgl * 512 + oc + r];
          I[Ibase + (size_t)(oc + r) * ISTRIDE + ul] = f2bf(acc[m][n][r] * ds);
        }
      }
    }
  }
}

// ---- blur + noise + bias + lrelu: one block per (oc, bl); 2-phase ----
__global__ __launch_bounds__(256) void k_blur(
    const unsigned short* __restrict__ I, const float* __restrict__ noise,
    const float* __restrict__ noise_w, const float* __restrict__ act_b,
    float* __restrict__ out, int b_base) {
  __shared__ __align__(16) unsigned short Ism[4][1096];
  __shared__ float V[64][67];
  const int oc = blockIdx.x, bl = blockIdx.y, b = b_base + bl;
  for (int i = threadIdx.x; i < 548; i += 256) {
    int p = i / 137, w = i - p * 137;
    *(uint4*)(&Ism[p][w * 8]) =
        *(const uint4*)(I + ((size_t)(bl * 4 + p) * 512 + oc) * ISTRIDE + w * 8);
  }
  __syncthreads();
  // vertical: V[qy][px*33+ux], planes p = py*2+px
  for (int i = threadIdx.x; i < 2112; i += 256) {
    int r = i / 66, col = i - r * 66;
    int px_ = (col >= 33), ux = col - 33 * px_;
    float v0 = (r >= 1) ? bf2f(Ism[2 + px_][(r - 1) * 33 + ux]) : 0.f;
    float a_ = bf2f(Ism[px_][r * 33 + ux]);
    float b_ = bf2f(Ism[2 + px_][r * 33 + ux]);
    float c_ = bf2f(Ism[px_][(r + 1) * 33 + ux]);
    float d_ = bf2f(Ism[2 + px_][(r + 1) * 33 + ux]);
    V[2 * r][col]     = 0.25f * v0 + 0.75f * a_ + 0.75f * b_ + 0.25f * c_;
    V[2 * r + 1][col] = 0.25f * a_ + 0.75f * b_ + 0.75f * c_ + 0.25f * d_;
  }
  __syncthreads();
  const float nw = noise_w[0], ab = act_b[oc];
  // horizontal: 4 output px per thread, float4 stores
  for (int i = threadIdx.x; i < 1024; i += 256) {
    int qy = i >> 4, r4 = i & 15;
    int rx = r4 * 2;
    float vA0 = V[qy][rx],     vB0 = V[qy][33 + rx];
    float vA1 = V[qy][rx + 1], vB1 = V[qy][33 + rx + 1];
    float vA2 = V[qy][rx + 2], vB2 = V[qy][33 + rx + 2];
    float w0 = (rx >= 1) ? V[qy][33 + rx - 1] : 0.f;
    float o0 = 0.25f * w0  + 0.75f * vA0 + 0.75f * vB0 + 0.25f * vA1;
    float o1 = 0.25f * vA0 + 0.75f * vB0 + 0.75f * vA1 + 0.25f * vB1;
    float o2 = 0.25f * vB0 + 0.75f * vA1 + 0.75f * vB1 + 0.25f * vA2;
    float o3 = 0.25f * vA1 + 0.75f * vB1 + 0.75f * vA2 + 0.25f * vB2;
    const float4 nv = *(const float4*)(noise + b * 4096 + qy * 64 + r4 * 4);
    o0 += nw * nv.x + ab;  o1 += nw * nv.y + ab;
    o2 += nw * nv.z + ab;  o3 += nw * nv.w + ab;
    o0 = (o0 > 0.f ? o0 : 0.2f * o0) * 1.4142135623730951f;
    o1 = (o1 > 0.f ? o1 : 0.2f * o1) * 1.4142135623730951f;
    o2 = (o2 > 0.f ? o2 : 0.2f * o2) * 1.4142135623730951f;
    o3 = (o3 > 0.f ? o3 : 0.2f * o3) * 1.4142135623730951f;
    float4 ov = make_float4(o0, o1, o2, o3);
    *(float4*)(out + (((size_t)b * 512 + oc) * 64 + qy) * 64 + r4 * 4) = ov;
  }
}

extern "C" void kernel_launch(void* const* d_in, const int* in_sizes, int n_in,
                              void* d_out, int out_size, void* d_ws, size_t ws_size,
                              hipStream_t stream) {
  const float* x       = (const float*)d_in[0];
  const float* style   = (const float*)d_in[1];
  const float* noise   = (const float*)d_in[2];
  const float* conv_w  = (const float*)d_in[3];
  const float* mod_w   = (const float*)d_in[4];
  const float* mod_b   = (const float*)d_in[5];
  const float* noise_w = (const float*)d_in[6];
  const float* act_b   = (const float*)d_in[7];
  float* out = (float*)d_out;

  char* ws = (char*)d_ws;
  float*          s_ws = (float*)ws;                                  // 32 KB
  float*          d_sc = (float*)(ws + 32768);                        // 32 KB
  float*          w2s  = (float*)(ws + 65536);                        // 1 MB
  unsigned short* S2   = (unsigned short*)(ws + 65536 + 1048576);               // 18.94 MB
  unsigned short* W2   = (unsigned short*)(ws + 65536 + 1048576 + 18939904);    // 4.72 MB
  unsigned short* I    = (unsigned short*)(ws + 65536 + 1048576 + 18939904 + 4718592);
  const size_t fixed = 65536ull + 1048576ull + 18939904ull + 4718592ull;  // 24.77 MB
  const size_t per_b = (size_t)4 * 512 * ISTRIDE * 2;                     // 4.72 MB/batch

  int nb = 16;                                  // batch chunk sized to ws budget
  if (ws_size < fixed + 16 * per_b) nb = 8;
  if (ws_size < fixed + 8 * per_b)  nb = 4;
  if (ws_size < fixed + 4 * per_b)  nb = 2;
  if (ws_size < fixed + 2 * per_b)  nb = 1;

  k_style<<<2048, 256, 0, stream>>>(style, mod_w, mod_b, s_ws);
  k_w2<<<512, 256, 0, stream>>>(conv_w, W2, w2s);
  k_demod<<<2048, 256, 0, stream>>>(w2s, s_ws, d_sc);
  k_xs2<<<dim3(16, 8, 16), 256, 0, stream>>>(x, s_ws, S2);
  k_zero<<<dim3(132, 16), 256, 0, stream>>>(S2);
  for (int b0 = 0; b0 < 16; b0 += nb) {
    int g      = (nb >= 2) ? 2 : 1;         // batches per N-group
    int ngrp   = nb / g;
    int ntiles = (g * 1089 + 255) / 256;    // 9 (g=2) or 5 (g=1)
    int run    = 4 * ntiles * 4;            // blocks per group (144 or 80)
    k_gemm<<<ngrp * run, 256, 0, stream>>>(S2, W2, d_sc, I, b0, g, ntiles, run);
    k_blur<<<dim3(512, nb), 256, 0, stream>>>(I, noise, noise_w, act_b, out, b0);
  }
}